// Round 1
// baseline (165.697 us; speedup 1.0000x reference)
//
#include <hip/hip_runtime.h>
#include <hip/hip_bf16.h>
#include <stdint.h>

// KAN layer: out[b,o] = sum_{i,k} basis(tanh(x[b,i]))[k] * coeffs[o,i,k]
// == GEMM  M=8192 (b), N=512 (o), K=4096 (i*8+k), A=basis (bf16, built in ws),
//          B^T = coeffs flattened (bf16 cast of [512][4096]).

#define M_TOTAL 8192
#define N_DIM   512
#define K_DIM   4096
#define BM 128
#define BN 64
#define BK 64

typedef __attribute__((ext_vector_type(8))) short short8;   // 8 x bf16 (guide §3)
typedef __attribute__((ext_vector_type(4))) float f32x4;

typedef const __attribute__((address_space(1))) uint32_t ga_u32;
typedef __attribute__((address_space(3))) uint32_t ls_u32;

__device__ __forceinline__ void gload_lds16(const void* g, void* l) {
  // async global->LDS, 16B/lane; LDS dest = wave-uniform base + lane*16
  __builtin_amdgcn_global_load_lds((ga_u32*)(uintptr_t)g,
                                   (ls_u32*)(uint32_t)(uintptr_t)l, 16, 0, 0);
}

__device__ __forceinline__ unsigned short f2bf(float f) {
  // RNE fp32->bf16 (finite inputs only)
  uint32_t u = __builtin_bit_cast(uint32_t, f);
  u = (u + 0x7FFFu + ((u >> 16) & 1u)) >> 16;
  return (unsigned short)u;
}

// ---------------- basis kernel: one thread per (b,i) element ----------------
__global__ __launch_bounds__(256) void basis_kernel(const float* __restrict__ x,
                                                    __hip_bfloat16* __restrict__ A,
                                                    int total) {
  int idx = blockIdx.x * 256 + threadIdx.x;
  if (idx >= total) return;
  float t = tanhf(x[idx]);
  const float h = 2.0f / 11.0f;           // GRID = linspace(-1,1,12), uniform
  float B[11];
#pragma unroll
  for (int j = 0; j < 11; ++j) {
    float gj  = -1.0f + h * (float)j;
    float gj1 = -1.0f + h * (float)(j + 1);
    B[j] = (t >= gj && t < gj1) ? 1.0f : 0.0f;
  }
#pragma unroll
  for (int k = 1; k <= 3; ++k) {
    float inv = 1.0f / (h * (float)k);    // dl = dr = k*h > EPS always
#pragma unroll
    for (int j = 0; j < 11 - k; ++j) {
      float gj   = -1.0f + h * (float)j;
      float gjk1 = -1.0f + h * (float)(j + k + 1);
      B[j] = (t - gj) * inv * B[j] + (gjk1 - t) * inv * B[j + 1];
    }
  }
  union { unsigned short us[8]; int4 v; } pack;
#pragma unroll
  for (int j = 0; j < 8; ++j) pack.us[j] = f2bf(B[j]);
  reinterpret_cast<int4*>(A)[idx] = pack.v;   // 16B coalesced store
}

// ---------------- coeff cast: [512][512][8] fp32 -> bf16 (== B^T[512][4096]) --
__global__ __launch_bounds__(256) void cvt_kernel(const float* __restrict__ c,
                                                  __hip_bfloat16* __restrict__ Bt,
                                                  int total8) {
  int idx = blockIdx.x * 256 + threadIdx.x;
  if (idx >= total8) return;
  const float4* cp = reinterpret_cast<const float4*>(c) + (size_t)idx * 2;
  float4 a = cp[0], b = cp[1];
  union { unsigned short us[8]; int4 v; } pack;
  pack.us[0] = f2bf(a.x); pack.us[1] = f2bf(a.y);
  pack.us[2] = f2bf(a.z); pack.us[3] = f2bf(a.w);
  pack.us[4] = f2bf(b.x); pack.us[5] = f2bf(b.y);
  pack.us[6] = f2bf(b.z); pack.us[7] = f2bf(b.w);
  reinterpret_cast<int4*>(Bt)[idx] = pack.v;
}

// ---------------- GEMM: C[m,n] = sum_k A[m,k] * Bt[n,k], fp32 out ------------
// block 256 thr = 4 waves (2x2), tile 128x64, BK=64, 16x16x32 bf16 MFMA.
// LDS layout: row-major [rows][8 chunks of 16B], chunk pos XOR-swizzled by
// (row&7) applied on the GLOBAL source index so global_load_lds's
// wave-uniform-base+lane*16 destination rule is honored; ds_read_b128
// fragment reads then hit banks 2-way (free per m136).
__global__ __launch_bounds__(256, 4) void gemm_kernel(
    const __hip_bfloat16* __restrict__ A,   // [rows][4096] chunk-local
    const __hip_bfloat16* __restrict__ Bt,  // [512][4096]
    float* __restrict__ C) {                // [rows][512] chunk-local
  __shared__ __hip_bfloat16 ldsA[BM * BK];  // 16 KB
  __shared__ __hip_bfloat16 ldsB[BN * BK];  // 8 KB

  const int tid   = threadIdx.x;
  const int wid   = tid >> 6;
  const int lane  = tid & 63;
  const int quad  = lane >> 4;
  const int l16   = lane & 15;
  const int waveM = wid >> 1;               // 0..1
  const int waveN = wid & 1;                // 0..1
  const int n0 = blockIdx.x * BN;           // 8 N-tiles fastest
  const int m0 = blockIdx.y * BM;

  // staging descriptors: slot s -> (row, physical chunk p); source chunk c = p ^ (row&7)
  uint32_t aGlob[4], aLds[4];
#pragma unroll
  for (int t = 0; t < 4; ++t) {
    int s = t * 256 + tid;
    int row = s >> 3, p = s & 7, c = p ^ (row & 7);
    aGlob[t] = (uint32_t)(m0 + row) * (uint32_t)K_DIM + (uint32_t)c * 8u;
    aLds[t]  = (uint32_t)s * 16u;
  }
  uint32_t bGlob[2], bLds[2];
#pragma unroll
  for (int t = 0; t < 2; ++t) {
    int s = t * 256 + tid;
    int row = s >> 3, p = s & 7, c = p ^ (row & 7);
    bGlob[t] = (uint32_t)(n0 + row) * (uint32_t)K_DIM + (uint32_t)c * 8u;
    bLds[t]  = (uint32_t)s * 16u;
  }

  // fragment LDS byte offsets: A[m=l16][k=quad*8+j], B[n=l16][k=quad*8+j]
  uint32_t aOff[2][4], bOff[2][2];
#pragma unroll
  for (int kk = 0; kk < 2; ++kk) {
    int c = kk * 4 + quad;
#pragma unroll
    for (int mi = 0; mi < 4; ++mi) {
      int row = waveM * 64 + mi * 16 + l16;
      aOff[kk][mi] = (uint32_t)(row * 8 + (c ^ (row & 7))) * 16u;
    }
#pragma unroll
    for (int ni = 0; ni < 2; ++ni) {
      int row = waveN * 32 + ni * 16 + l16;
      bOff[kk][ni] = (uint32_t)(row * 8 + (c ^ (row & 7))) * 16u;
    }
  }

  char* ldsAc = (char*)ldsA;
  char* ldsBc = (char*)ldsB;

  f32x4 acc[4][2];
#pragma unroll
  for (int mi = 0; mi < 4; ++mi)
#pragma unroll
    for (int ni = 0; ni < 2; ++ni)
      acc[mi][ni] = (f32x4){0.f, 0.f, 0.f, 0.f};

  for (int kt = 0; kt < K_DIM; kt += BK) {
    __syncthreads();                        // prev tile fully consumed
#pragma unroll
    for (int t = 0; t < 4; ++t) gload_lds16(A + aGlob[t] + kt, ldsAc + aLds[t]);
#pragma unroll
    for (int t = 0; t < 2; ++t) gload_lds16(Bt + bGlob[t] + kt, ldsBc + bLds[t]);
    __syncthreads();                        // drains vmcnt(0): staging visible
#pragma unroll
    for (int kk = 0; kk < 2; ++kk) {
      short8 af[4], bf[2];
#pragma unroll
      for (int mi = 0; mi < 4; ++mi)
        af[mi] = *reinterpret_cast<const short8*>(ldsAc + aOff[kk][mi]);
#pragma unroll
      for (int ni = 0; ni < 2; ++ni)
        bf[ni] = *reinterpret_cast<const short8*>(ldsBc + bOff[kk][ni]);
#pragma unroll
      for (int mi = 0; mi < 4; ++mi)
#pragma unroll
        for (int ni = 0; ni < 2; ++ni)
          acc[mi][ni] = __builtin_amdgcn_mfma_f32_16x16x32_bf16(
              af[mi], bf[ni], acc[mi][ni], 0, 0, 0);
    }
  }

  // epilogue: D row = quad*4 + r, col = l16 (m89/m91-verified C/D layout)
#pragma unroll
  for (int mi = 0; mi < 4; ++mi) {
#pragma unroll
    for (int ni = 0; ni < 2; ++ni) {
      int col = n0 + waveN * 32 + ni * 16 + l16;
#pragma unroll
      for (int r = 0; r < 4; ++r) {
        int row = m0 + waveM * 64 + mi * 16 + quad * 4 + r;
        C[(size_t)row * N_DIM + col] = acc[mi][ni][r];
      }
    }
  }
}

extern "C" void kernel_launch(void* const* d_in, const int* in_sizes, int n_in,
                              void* d_out, int out_size, void* d_ws, size_t ws_size,
                              hipStream_t stream) {
  const float* x    = (const float*)d_in[0];   // [8192,512]
  const float* coef = (const float*)d_in[1];   // [512,512,8]
  float* out = (float*)d_out;                  // [8192,512]

  const size_t BT_BYTES = (size_t)N_DIM * K_DIM * 2;     // 4 MB
  __hip_bfloat16* Bt = (__hip_bfloat16*)d_ws;
  __hip_bfloat16* A  = (__hip_bfloat16*)((char*)d_ws + BT_BYTES);

  size_t avail = (ws_size > BT_BYTES) ? ws_size - BT_BYTES : 0;
  long maxRows = (long)(avail / ((size_t)K_DIM * 2));
  maxRows = (maxRows / BM) * BM;
  if (maxRows > M_TOTAL) maxRows = M_TOTAL;
  if (maxRows < BM) maxRows = BM;   // assume ws >= ~5 MB

  const int total8 = N_DIM * K_DIM / 8;   // 262144
  cvt_kernel<<<(total8 + 255) / 256, 256, 0, stream>>>(coef, Bt, total8);

  for (long r0 = 0; r0 < M_TOTAL; r0 += maxRows) {
    long rows  = (M_TOTAL - r0 < maxRows) ? (M_TOTAL - r0) : maxRows;
    long total = rows * 512;
    basis_kernel<<<(int)((total + 255) / 256), 256, 0, stream>>>(
        x + r0 * 512, A, (int)total);
    dim3 grid(N_DIM / BN, (unsigned)(rows / BM));
    gemm_kernel<<<grid, 256, 0, stream>>>(A, Bt, out + r0 * N_DIM);
  }
}

// Round 2
// 144.568 us; speedup vs baseline: 1.1461x; 1.1461x over previous
//
#include <hip/hip_runtime.h>
#include <hip/hip_bf16.h>
#include <stdint.h>

// KAN layer: out[b,o] = sum_{i,k} basis(tanh(x[b,i]))[k] * coeffs[o,i,k]
// == GEMM  M=8192 (b), N=512 (o), K=4096 (i*8+k), A=basis (bf16, ws),
//          B^T = coeffs flattened (bf16 cast of [512][4096]).

#define M_TOTAL 8192
#define N_DIM   512
#define K_DIM   4096
#define BM 128
#define BN 128
#define BK 64
#define BUF_BYTES ((BM + BN) * BK * 2)   // 32 KB per LDS buffer

typedef __attribute__((ext_vector_type(8))) short short8;   // 8 x bf16
typedef __attribute__((ext_vector_type(4))) float f32x4;

typedef const __attribute__((address_space(1))) uint32_t ga_u32;
typedef __attribute__((address_space(3))) uint32_t ls_u32;

__device__ __forceinline__ void gload_lds16(const void* g, void* l) {
  // async global->LDS, 16B/lane; LDS dest = wave-uniform base + lane*16
  __builtin_amdgcn_global_load_lds((ga_u32*)(uintptr_t)g,
                                   (ls_u32*)(uint32_t)(uintptr_t)l, 16, 0, 0);
}

__device__ __forceinline__ unsigned short f2bf(float f) {
  uint32_t u = __builtin_bit_cast(uint32_t, f);
  u = (u + 0x7FFFu + ((u >> 16) & 1u)) >> 16;
  return (unsigned short)u;
}

// ---------------- basis kernel: cardinal cubic B-spline, uniform knots -------
// GRID = linspace(-1,1,12), h = 2/11. t = tanh(x) in (-1,1) -> cell c,
// local u; only 4 bases non-zero: indices c-3..c get the standard uniform
// cubic B-spline weights (algebraically identical to the Cox-de Boor ref).
__global__ __launch_bounds__(256) void basis_kernel(const float* __restrict__ x,
                                                    __hip_bfloat16* __restrict__ A,
                                                    int total) {
  int idx = blockIdx.x * 256 + threadIdx.x;
  if (idx >= total) return;
  float xv = x[idx];
  xv = fminf(15.f, fmaxf(-15.f, xv));
  float e = __expf(2.0f * xv);                       // native v_exp_f32 path
  float t = (e - 1.0f) * __builtin_amdgcn_rcpf(e + 1.0f);   // tanh
  float uf = (t + 1.0f) * 5.5f;                      // / h = *11/2
  int c = (int)uf;                                   // cell 0..10
  c = c > 10 ? 10 : c;
  float u  = uf - (float)c;
  float u2 = u * u, u3 = u2 * u;
  float om = 1.0f - u;
  float w0 = om * om * om * (1.0f / 6.0f);                       // basis c-3
  float w1 = (3.0f * u3 - 6.0f * u2 + 4.0f) * (1.0f / 6.0f);    // basis c-2
  float w2 = (-3.0f * u3 + 3.0f * u2 + 3.0f * u + 1.0f) * (1.0f / 6.0f); // c-1
  float w3 = u3 * (1.0f / 6.0f);                                 // basis c
  union { unsigned short us[8]; int4 v; } pk;
#pragma unroll
  for (int j = 0; j < 8; ++j) {
    int i = j - c + 3;                       // which weight lands on basis j
    float v = (i == 0) ? w0 : (i == 1) ? w1 : (i == 2) ? w2 : (i == 3) ? w3 : 0.f;
    pk.us[j] = f2bf(v);
  }
  reinterpret_cast<int4*>(A)[idx] = pk.v;    // 16B coalesced store
}

// ---------------- coeff cast: [512][512][8] fp32 -> bf16 (== B^T[512][4096]) --
__global__ __launch_bounds__(256) void cvt_kernel(const float* __restrict__ c,
                                                  __hip_bfloat16* __restrict__ Bt,
                                                  int total8) {
  int idx = blockIdx.x * 256 + threadIdx.x;
  if (idx >= total8) return;
  const float4* cp = reinterpret_cast<const float4*>(c) + (size_t)idx * 2;
  float4 a = cp[0], b = cp[1];
  union { unsigned short us[8]; int4 v; } pack;
  pack.us[0] = f2bf(a.x); pack.us[1] = f2bf(a.y);
  pack.us[2] = f2bf(a.z); pack.us[3] = f2bf(a.w);
  pack.us[4] = f2bf(b.x); pack.us[5] = f2bf(b.y);
  pack.us[6] = f2bf(b.z); pack.us[7] = f2bf(b.w);
  reinterpret_cast<int4*>(Bt)[idx] = pack.v;
}

// ---------------- GEMM: C[m,n] = sum_k A[m,k]*Bt[n,k] ------------------------
// 128x128 tile, 256 thr = 4 waves (2x2), each wave 64x64 (4x4 frags),
// BK=64, 16x16x32 bf16 MFMA. Double-buffered LDS, ONE barrier per K-tile:
// stage tile k+1 right after the barrier, compute tile k underneath it —
// at 1 block/CU (grid=256) there is no other wave to hide the load latency,
// so this dbuf is load-bearing (unlike m99/m100's 3-block/CU case).
// LDS chunk XOR-swizzle by (row&7) applied on the GLOBAL source index keeps
// global_load_lds's wave-uniform-base+lane*16 rule; ds_read_b128 frag reads
// then hit banks 2-way (free per m136).
__global__ __launch_bounds__(256) void gemm_kernel(
    const __hip_bfloat16* __restrict__ A,   // [rows][4096]
    const __hip_bfloat16* __restrict__ Bt,  // [512][4096]
    float* __restrict__ C) {                // [rows][512]
  __shared__ __hip_bfloat16 lds[2 * (BM + BN) * BK];   // 64 KB

  const int tid   = threadIdx.x;
  const int wid   = tid >> 6;
  const int lane  = tid & 63;
  const int quad  = lane >> 4;
  const int l16   = lane & 15;
  const int waveM = wid >> 1;               // 0..1
  const int waveN = wid & 1;                // 0..1

  // XCD-aware decode: group the 4 N-blocks of each M-stripe on one XCD so
  // they share the A stripe in that XCD's L2 (A re-reads hit L2, not L3).
  int b = blockIdx.x, mt, nt;
  int nm = gridDim.x >> 2;                  // number of M tiles
  if ((nm & 7) == 0) {
    int xcd = b & 7, q = b >> 3, per = nm >> 3;
    mt = xcd * per + (q >> 2);
    nt = q & 3;
  } else { mt = b >> 2; nt = b & 3; }
  const int m0 = mt * BM;
  const int n0 = nt * BN;

  // staging: slot s -> (row, phys chunk p); source chunk cc = p ^ (row&7)
  uint32_t aGlob[4], bGlob[4], sLds[4];
#pragma unroll
  for (int t = 0; t < 4; ++t) {
    int s = t * 256 + tid;
    int row = s >> 3, p = s & 7, cc = p ^ (row & 7);
    aGlob[t] = (uint32_t)(m0 + row) * (uint32_t)K_DIM + (uint32_t)cc * 8u;
    bGlob[t] = (uint32_t)(n0 + row) * (uint32_t)K_DIM + (uint32_t)cc * 8u;
    sLds[t]  = (uint32_t)s * 16u;           // A at buf+0, B at buf+16KB
  }

  // fragment LDS byte offsets (within a buffer)
  uint32_t aOff[2][4], bOff[2][4];
#pragma unroll
  for (int kk = 0; kk < 2; ++kk) {
    int c = kk * 4 + quad;
#pragma unroll
    for (int mi = 0; mi < 4; ++mi) {
      int row = waveM * 64 + mi * 16 + l16;
      aOff[kk][mi] = (uint32_t)(row * 8 + (c ^ (row & 7))) * 16u;
    }
#pragma unroll
    for (int ni = 0; ni < 4; ++ni) {
      int row = waveN * 64 + ni * 16 + l16;
      bOff[kk][ni] = (uint32_t)(BM * BK * 2) + (uint32_t)(row * 8 + (c ^ (row & 7))) * 16u;
    }
  }

  char* ldsc = (char*)lds;

  f32x4 acc[4][4];
#pragma unroll
  for (int mi = 0; mi < 4; ++mi)
#pragma unroll
    for (int ni = 0; ni < 4; ++ni)
      acc[mi][ni] = (f32x4){0.f, 0.f, 0.f, 0.f};

  const int NT = K_DIM / BK;                // 64 K-tiles

  // prologue: stage tile 0 into buffer 0
#pragma unroll
  for (int t = 0; t < 4; ++t) {
    gload_lds16(A + aGlob[t], ldsc + sLds[t]);
    gload_lds16(Bt + bGlob[t], ldsc + BM * BK * 2 + sLds[t]);
  }

  for (int it = 0; it < NT; ++it) {
    const int cur = it & 1;
    char* bufc = ldsc + cur * BUF_BYTES;
    __syncthreads();                        // drains staging into buf[cur]
    if (it + 1 < NT) {                      // stage k+1 under compute of k
      char* bufn = ldsc + (1 - cur) * BUF_BYTES;
      uint32_t kt = (uint32_t)(it + 1) * BK;
#pragma unroll
      for (int t = 0; t < 4; ++t) {
        gload_lds16(A + aGlob[t] + kt, bufn + sLds[t]);
        gload_lds16(Bt + bGlob[t] + kt, bufn + BM * BK * 2 + sLds[t]);
      }
    }
#pragma unroll
    for (int kk = 0; kk < 2; ++kk) {
      short8 af[4], bf[4];
#pragma unroll
      for (int mi = 0; mi < 4; ++mi)
        af[mi] = *reinterpret_cast<const short8*>(bufc + aOff[kk][mi]);
#pragma unroll
      for (int ni = 0; ni < 4; ++ni)
        bf[ni] = *reinterpret_cast<const short8*>(bufc + bOff[kk][ni]);
#pragma unroll
      for (int mi = 0; mi < 4; ++mi)
#pragma unroll
        for (int ni = 0; ni < 4; ++ni)
          acc[mi][ni] = __builtin_amdgcn_mfma_f32_16x16x32_bf16(
              af[mi], bf[ni], acc[mi][ni], 0, 0, 0);
    }
  }

  // epilogue: D row = quad*4 + r, col = l16 (m89/m91-verified C/D layout)
#pragma unroll
  for (int mi = 0; mi < 4; ++mi) {
#pragma unroll
    for (int ni = 0; ni < 4; ++ni) {
      int col = n0 + waveN * 64 + ni * 16 + l16;
#pragma unroll
      for (int r = 0; r < 4; ++r) {
        int row = m0 + waveM * 64 + mi * 16 + quad * 4 + r;
        C[(size_t)row * N_DIM + col] = acc[mi][ni][r];
      }
    }
  }
}

extern "C" void kernel_launch(void* const* d_in, const int* in_sizes, int n_in,
                              void* d_out, int out_size, void* d_ws, size_t ws_size,
                              hipStream_t stream) {
  const float* x    = (const float*)d_in[0];   // [8192,512]
  const float* coef = (const float*)d_in[1];   // [512,512,8]
  float* out = (float*)d_out;                  // [8192,512]

  const size_t BT_BYTES = (size_t)N_DIM * K_DIM * 2;     // 4 MB
  __hip_bfloat16* Bt = (__hip_bfloat16*)d_ws;
  __hip_bfloat16* A  = (__hip_bfloat16*)((char*)d_ws + BT_BYTES);

  size_t avail = (ws_size > BT_BYTES) ? ws_size - BT_BYTES : 0;
  long maxRows = (long)(avail / ((size_t)K_DIM * 2));
  maxRows = (maxRows / BM) * BM;
  if (maxRows > M_TOTAL) maxRows = M_TOTAL;
  if (maxRows < BM) maxRows = BM;   // assume ws >= ~5 MB

  const int total8 = N_DIM * K_DIM / 8;   // 262144
  cvt_kernel<<<(total8 + 255) / 256, 256, 0, stream>>>(coef, Bt, total8);

  for (long r0 = 0; r0 < M_TOTAL; r0 += maxRows) {
    long rows  = (M_TOTAL - r0 < maxRows) ? (M_TOTAL - r0) : maxRows;
    long total = rows * 512;
    basis_kernel<<<(int)((total + 255) / 256), 256, 0, stream>>>(
        x + r0 * 512, A, (int)total);
    dim3 grid((unsigned)((rows / BM) * (N_DIM / BN)));
    gemm_kernel<<<grid, 256, 0, stream>>>(A, Bt, out + r0 * N_DIM);
  }
}